// Round 1
// baseline (4754.058 us; speedup 1.0000x reference)
//
#include <hip/hip_runtime.h>
#include <hip/hip_bf16.h>
#include <math.h>

// Problem constants (match reference)
#define BB 8
#define NN 1024
#define MM 1024
#define CC 512
#define SS 2048
#define KK 16
#define PH 64
#define AH 1024
#define EPSV 1e-5f

// ---------------------------------------------------------------------------
// Kernel 1: KNN. One block = 256 threads = 4 waves = 4 queries (same batch).
// Stages all 2048 candidate coords + squared norms in LDS, each wave finds
// its query's 16 nearest via 16 rounds of masked wave-argmin.
// ---------------------------------------------------------------------------
__global__ __launch_bounds__(256) void knn_kernel(
    const float* __restrict__ pcd, const float* __restrict__ pcd_fb,
    int* __restrict__ knn) {
  __shared__ float sx[SS], sy[SS], sz[SS], ss[SS];
  const int t = threadIdx.x;
  const int b = blockIdx.x >> 8;             // 256 blocks per batch
  const int nbase = (blockIdx.x & 255) * 4;
  for (int s = t; s < SS; s += 256) {
    float x, y, z;
    if (s < NN) {
      x = pcd[(b * 3 + 0) * NN + s];
      y = pcd[(b * 3 + 1) * NN + s];
      z = pcd[(b * 3 + 2) * NN + s];
    } else {
      int s2 = s - NN;
      x = pcd_fb[(b * 3 + 0) * MM + s2];
      y = pcd_fb[(b * 3 + 1) * MM + s2];
      z = pcd_fb[(b * 3 + 2) * MM + s2];
    }
    sx[s] = x; sy[s] = y; sz[s] = z;
    ss[s] = x * x + y * y + z * z;
  }
  __syncthreads();
  const int wv = t >> 6, lane = t & 63;
  const int n = nbase + wv;
  const float qx = sx[n], qy = sy[n], qz = sz[n];
  const float qq = qx * qx + qy * qy + qz * qz;
  float d[32];
#pragma unroll
  for (int i = 0; i < 32; ++i) {
    int s = i * 64 + lane;                  // lane-contiguous -> bank-free
    d[i] = qq - 2.0f * (qx * sx[s] + qy * sy[s] + qz * sz[s]) + ss[s];
  }
  unsigned mask = 0;
  int win = -1;
#pragma unroll
  for (int r = 0; r < 16; ++r) {
    float best = 3.4e38f;
    int bi = 0x7fffffff;
#pragma unroll
    for (int i = 0; i < 32; ++i) {
      if (!((mask >> i) & 1) && d[i] < best) { best = d[i]; bi = i * 64 + lane; }
    }
#pragma unroll
    for (int off = 32; off >= 1; off >>= 1) {
      float ov = __shfl_xor(best, off);
      int oi = __shfl_xor(bi, off);
      if (ov < best || (ov == best && oi < bi)) { best = ov; bi = oi; }
    }
    if ((bi & 63) == lane) mask |= 1u << (bi >> 6);
    if (lane == r) win = bi;
  }
  if (lane < 16) knn[((size_t)b * NN + n) * KK + lane] = win;
}

// ---------------------------------------------------------------------------
// Kernel 2: per-query gather + pos MLP; writes X = qk_rel + pos_emb and
// V = group_feat + pos_emb for one chunk of queries. One block per query.
// ---------------------------------------------------------------------------
__global__ __launch_bounds__(256) void build_xv(
    int b, int n0,
    const float* __restrict__ pcd, const float* __restrict__ feat,
    const float* __restrict__ pcd_fb, const float* __restrict__ feat_fb,
    const float* __restrict__ pw1, const float* __restrict__ pb1,
    const float* __restrict__ pg, const float* __restrict__ pbeta,
    const float* __restrict__ pm, const float* __restrict__ pv,
    const float* __restrict__ pw2, const float* __restrict__ pb2,
    const int* __restrict__ knn,
    float* __restrict__ X, float* __restrict__ V, int LDB) {
  __shared__ int idx_sh[KK];
  __shared__ float prel[3][KK];
  __shared__ float h1r[PH * KK];
  const int t = threadIdx.x;
  const int n = n0 + blockIdx.x;
  if (t < KK) idx_sh[t] = knn[((size_t)b * NN + n) * KK + t];
  __syncthreads();
  if (t < 3 * KK) {
    int dd = t >> 4, k = t & 15;
    int s = idx_sh[k];
    float gp = (s < NN) ? pcd[(b * 3 + dd) * NN + s]
                        : pcd_fb[(b * 3 + dd) * MM + (s - NN)];
    float q = pcd[(b * 3 + dd) * NN + n];
    prel[dd][k] = q - gp;
  }
  __syncthreads();
  for (int e = t; e < PH * KK; e += 256) {
    int h = e >> 4, k = e & 15;
    float v = pb1[h] + pw1[h * 3 + 0] * prel[0][k] + pw1[h * 3 + 1] * prel[1][k]
            + pw1[h * 3 + 2] * prel[2][k];
    float sc = pg[h] * rsqrtf(pv[h] + EPSV);
    v = (v - pm[h]) * sc + pbeta[h];
    h1r[h * KK + k] = fmaxf(v, 0.0f);
  }
  __syncthreads();
  const int k = t & 15, coff = t >> 4;
  const int s = idx_sh[k];
  const size_t colbase = (size_t)(n - n0) * KK;
  for (int cb = 0; cb < CC / 16; ++cb) {
    int c = cb * 16 + coff;
    float fq = feat[((size_t)b * CC + c) * NN + n];
    float gf = (s < NN) ? feat[((size_t)b * CC + c) * NN + s]
                        : feat_fb[((size_t)b * CC + c) * MM + (s - NN)];
    float pe = pb2[c];
#pragma unroll
    for (int h = 0; h < PH; h += 4) {
      float4 w4 = *(const float4*)&pw2[c * PH + h];
      pe += w4.x * h1r[(h + 0) * KK + k];
      pe += w4.y * h1r[(h + 1) * KK + k];
      pe += w4.z * h1r[(h + 2) * KK + k];
      pe += w4.w * h1r[(h + 3) * KK + k];
    }
    X[(size_t)c * LDB + colbase + k] = fq - gf + pe;
    V[(size_t)c * LDB + colbase + k] = gf + pe;
  }
}

// ---------------------------------------------------------------------------
// Kernel 3: A1R = relu(bn(W1 @ X + b1)).  M=1024 (h), K=512, N=LDB cols.
// 128x128 tile, BK=16, 256 threads, 8x8 microtile.
// ---------------------------------------------------------------------------
__global__ __launch_bounds__(256) void gemm1(
    const float* __restrict__ W, const float* __restrict__ bias,
    const float* __restrict__ g, const float* __restrict__ beta,
    const float* __restrict__ mean, const float* __restrict__ var,
    const float* __restrict__ X, float* __restrict__ O, int LDB) {
  __shared__ float As[16 * 128];
  __shared__ float Bs[16 * 128];
  const int t = threadIdx.x;
  const int tx = t & 15, ty = t >> 4;
  const int h0 = blockIdx.y * 128;
  const size_t col0 = (size_t)blockIdx.x * 128;
  const int hi = t >> 1, kk0 = (t & 1) * 8;
  const int bkk = t >> 4, bci = (t & 15) * 8;
  float acc[8][8] = {};
  for (int k0 = 0; k0 < CC; k0 += 16) {
    float4 a0 = *(const float4*)&W[(size_t)(h0 + hi) * CC + k0 + kk0];
    float4 a1 = *(const float4*)&W[(size_t)(h0 + hi) * CC + k0 + kk0 + 4];
    float4 b0 = *(const float4*)&X[(size_t)(k0 + bkk) * LDB + col0 + bci];
    float4 b1 = *(const float4*)&X[(size_t)(k0 + bkk) * LDB + col0 + bci + 4];
    __syncthreads();
    As[(kk0 + 0) * 128 + hi] = a0.x;
    As[(kk0 + 1) * 128 + hi] = a0.y;
    As[(kk0 + 2) * 128 + hi] = a0.z;
    As[(kk0 + 3) * 128 + hi] = a0.w;
    As[(kk0 + 4) * 128 + hi] = a1.x;
    As[(kk0 + 5) * 128 + hi] = a1.y;
    As[(kk0 + 6) * 128 + hi] = a1.z;
    As[(kk0 + 7) * 128 + hi] = a1.w;
    *(float4*)&Bs[bkk * 128 + bci] = b0;
    *(float4*)&Bs[bkk * 128 + bci + 4] = b1;
    __syncthreads();
#pragma unroll
    for (int kk = 0; kk < 16; ++kk) {
      float4 A0 = *(const float4*)&As[kk * 128 + ty * 8];
      float4 A1 = *(const float4*)&As[kk * 128 + ty * 8 + 4];
      float4 B0 = *(const float4*)&Bs[kk * 128 + tx * 8];
      float4 B1 = *(const float4*)&Bs[kk * 128 + tx * 8 + 4];
      float ar[8] = {A0.x, A0.y, A0.z, A0.w, A1.x, A1.y, A1.z, A1.w};
      float br[8] = {B0.x, B0.y, B0.z, B0.w, B1.x, B1.y, B1.z, B1.w};
#pragma unroll
      for (int r = 0; r < 8; ++r)
#pragma unroll
        for (int c = 0; c < 8; ++c) acc[r][c] += ar[r] * br[c];
    }
  }
#pragma unroll
  for (int j = 0; j < 8; ++j) {
    int h = h0 + ty * 8 + j;
    float sc = g[h] * rsqrtf(var[h] + EPSV);
    float bb = bias[h], mn = mean[h], bt = beta[h];
    float vals[8];
#pragma unroll
    for (int i = 0; i < 8; ++i) {
      float vv = (acc[j][i] + bb - mn) * sc + bt;
      vals[i] = fmaxf(vv, 0.0f);
    }
    *(float4*)&O[(size_t)h * LDB + col0 + tx * 8] =
        make_float4(vals[0], vals[1], vals[2], vals[3]);
    *(float4*)&O[(size_t)h * LDB + col0 + tx * 8 + 4] =
        make_float4(vals[4], vals[5], vals[6], vals[7]);
  }
}

// ---------------------------------------------------------------------------
// Kernel 4: w = W2 @ A1R + b2; softmax over K=16; out = sum_k w~ * V.
// M=512 (c), K=1024, fused epilogue via LDS w-tile (stride 132, bank-safe).
// ---------------------------------------------------------------------------
__global__ __launch_bounds__(256) void gemm2(
    int b, int n0,
    const float* __restrict__ W, const float* __restrict__ bias,
    const float* __restrict__ A1R, const float* __restrict__ V,
    float* __restrict__ out, int LDB) {
  __shared__ float sm[128 * 132];
  float* As = sm;
  float* Bs = sm + 2048;
  const int t = threadIdx.x;
  const int tx = t & 15, ty = t >> 4;
  const int c0 = blockIdx.y * 128;
  const size_t col0 = (size_t)blockIdx.x * 128;
  const int hi = t >> 1, kk0 = (t & 1) * 8;
  const int bkk = t >> 4, bci = (t & 15) * 8;
  float acc[8][8] = {};
  for (int k0 = 0; k0 < AH; k0 += 16) {
    float4 a0 = *(const float4*)&W[(size_t)(c0 + hi) * AH + k0 + kk0];
    float4 a1 = *(const float4*)&W[(size_t)(c0 + hi) * AH + k0 + kk0 + 4];
    float4 b0 = *(const float4*)&A1R[(size_t)(k0 + bkk) * LDB + col0 + bci];
    float4 b1 = *(const float4*)&A1R[(size_t)(k0 + bkk) * LDB + col0 + bci + 4];
    __syncthreads();
    As[(kk0 + 0) * 128 + hi] = a0.x;
    As[(kk0 + 1) * 128 + hi] = a0.y;
    As[(kk0 + 2) * 128 + hi] = a0.z;
    As[(kk0 + 3) * 128 + hi] = a0.w;
    As[(kk0 + 4) * 128 + hi] = a1.x;
    As[(kk0 + 5) * 128 + hi] = a1.y;
    As[(kk0 + 6) * 128 + hi] = a1.z;
    As[(kk0 + 7) * 128 + hi] = a1.w;
    *(float4*)&Bs[bkk * 128 + bci] = b0;
    *(float4*)&Bs[bkk * 128 + bci + 4] = b1;
    __syncthreads();
#pragma unroll
    for (int kk = 0; kk < 16; ++kk) {
      float4 A0 = *(const float4*)&As[kk * 128 + ty * 8];
      float4 A1 = *(const float4*)&As[kk * 128 + ty * 8 + 4];
      float4 B0 = *(const float4*)&Bs[kk * 128 + tx * 8];
      float4 B1 = *(const float4*)&Bs[kk * 128 + tx * 8 + 4];
      float ar[8] = {A0.x, A0.y, A0.z, A0.w, A1.x, A1.y, A1.z, A1.w};
      float br[8] = {B0.x, B0.y, B0.z, B0.w, B1.x, B1.y, B1.z, B1.w};
#pragma unroll
      for (int r = 0; r < 8; ++r)
#pragma unroll
        for (int c = 0; c < 8; ++c) acc[r][c] += ar[r] * br[c];
    }
  }
  __syncthreads();  // done with As/Bs -> reuse region as w-tile
#pragma unroll
  for (int j = 0; j < 8; ++j) {
    int c = c0 + ty * 8 + j;
    float bb = bias[c];
    *(float4*)&sm[(ty * 8 + j) * 132 + tx * 8] =
        make_float4(acc[j][0] + bb, acc[j][1] + bb, acc[j][2] + bb, acc[j][3] + bb);
    *(float4*)&sm[(ty * 8 + j) * 132 + tx * 8 + 4] =
        make_float4(acc[j][4] + bb, acc[j][5] + bb, acc[j][6] + bb, acc[j][7] + bb);
  }
  __syncthreads();
#pragma unroll
  for (int e0 = 0; e0 < 4; ++e0) {
    int e = t + e0 * 256;
    int qi = e & 7, ci = e >> 3;
    float4 w0 = *(const float4*)&sm[ci * 132 + qi * 16];
    float4 w1 = *(const float4*)&sm[ci * 132 + qi * 16 + 4];
    float4 w2 = *(const float4*)&sm[ci * 132 + qi * 16 + 8];
    float4 w3 = *(const float4*)&sm[ci * 132 + qi * 16 + 12];
    float w[16] = {w0.x, w0.y, w0.z, w0.w, w1.x, w1.y, w1.z, w1.w,
                   w2.x, w2.y, w2.z, w2.w, w3.x, w3.y, w3.z, w3.w};
    float mx = w[0];
#pragma unroll
    for (int kq = 1; kq < 16; ++kq) mx = fmaxf(mx, w[kq]);
    float ex[16], ssum = 0.0f;
#pragma unroll
    for (int kq = 0; kq < 16; ++kq) { ex[kq] = __expf(w[kq] - mx); ssum += ex[kq]; }
    const float* vp = &V[(size_t)(c0 + ci) * LDB + col0 + qi * 16];
    float4 v0 = *(const float4*)&vp[0];
    float4 v1 = *(const float4*)&vp[4];
    float4 v2 = *(const float4*)&vp[8];
    float4 v3 = *(const float4*)&vp[12];
    float vv[16] = {v0.x, v0.y, v0.z, v0.w, v1.x, v1.y, v1.z, v1.w,
                    v2.x, v2.y, v2.z, v2.w, v3.x, v3.y, v3.z, v3.w};
    float dot = 0.0f;
#pragma unroll
    for (int kq = 0; kq < 16; ++kq) dot += ex[kq] * vv[kq];
    out[((size_t)b * CC + c0 + ci) * NN + n0 + (col0 >> 4) + qi] = dot / ssum;
  }
}

// ---------------------------------------------------------------------------
extern "C" void kernel_launch(void* const* d_in, const int* in_sizes, int n_in,
                              void* d_out, int out_size, void* d_ws, size_t ws_size,
                              hipStream_t stream) {
  const float* pcd     = (const float*)d_in[0];
  const float* feat    = (const float*)d_in[1];
  const float* pcd_fb  = (const float*)d_in[2];
  const float* feat_fb = (const float*)d_in[3];
  const float* pw1     = (const float*)d_in[4];
  const float* pb1     = (const float*)d_in[5];
  const float* pg      = (const float*)d_in[6];
  const float* pbeta   = (const float*)d_in[7];
  const float* pm      = (const float*)d_in[8];
  const float* pv      = (const float*)d_in[9];
  const float* pw2     = (const float*)d_in[10];
  const float* pb2     = (const float*)d_in[11];
  const float* aw1     = (const float*)d_in[12];
  const float* ab1     = (const float*)d_in[13];
  const float* ag      = (const float*)d_in[14];
  const float* abeta   = (const float*)d_in[15];
  const float* am      = (const float*)d_in[16];
  const float* av      = (const float*)d_in[17];
  const float* aw2     = (const float*)d_in[18];
  const float* ab2     = (const float*)d_in[19];
  float* out = (float*)d_out;

  int* idx_ws = (int*)d_ws;                       // B*N*K ints = 512 KB
  const size_t idx_bytes = (size_t)BB * NN * KK * sizeof(int);
  // Per-query ws bytes: X (512*16*4) + V (512*16*4) + A1R (1024*16*4) = 128 KB
  int QC = 1024;
  while (QC > 8 && idx_bytes + (size_t)QC * 131072 > ws_size) QC >>= 1;
  const int LDB = QC * KK;
  float* Xp  = (float*)((char*)d_ws + idx_bytes);
  float* Vp  = Xp + (size_t)CC * LDB;
  float* A1R = Vp + (size_t)CC * LDB;

  knn_kernel<<<dim3(BB * NN / 4), 256, 0, stream>>>(pcd, pcd_fb, idx_ws);

  for (int b = 0; b < BB; ++b) {
    for (int n0 = 0; n0 < NN; n0 += QC) {
      build_xv<<<dim3(QC), 256, 0, stream>>>(
          b, n0, pcd, feat, pcd_fb, feat_fb,
          pw1, pb1, pg, pbeta, pm, pv, pw2, pb2, idx_ws, Xp, Vp, LDB);
      gemm1<<<dim3(LDB / 128, AH / 128), 256, 0, stream>>>(
          aw1, ab1, ag, abeta, am, av, Xp, A1R, LDB);
      gemm2<<<dim3(LDB / 128, CC / 128), 256, 0, stream>>>(
          b, n0, aw2, ab2, A1R, Vp, out, LDB);
    }
  }
}

// Round 4
// 1560.131 us; speedup vs baseline: 3.0472x; 3.0472x over previous
//
#include <hip/hip_runtime.h>
#include <math.h>

#define BB 8
#define NN 1024
#define MM 1024
#define CC 512
#define SS 2048
#define KK 16
#define PH 64
#define AH 1024
#define COLS (NN * KK)
#define EPSV 1e-5f

typedef _Float16 half8 __attribute__((ext_vector_type(8)));
typedef _Float16 half4 __attribute__((ext_vector_type(4)));
typedef float f32x4 __attribute__((ext_vector_type(4)));

// ---------------------------------------------------------------------------
// global->LDS direct copy, 16B per lane. Dest is wave-uniform base + lane*16.
// ---------------------------------------------------------------------------
__device__ __forceinline__ void gl_lds16(const void* g, void* l) {
  __builtin_amdgcn_global_load_lds(
      (const __attribute__((address_space(1))) unsigned int*)g,
      (__attribute__((address_space(3))) unsigned int*)l, 16, 0, 0);
}

// Involution swizzle on LDS byte offsets: XOR bits 4-5 with bits 7-8.
// Makes ds_read_b128 fragment reads (16 rows x 64B-row tiles) conflict-free.
__device__ __forceinline__ int swz(int x) { return x ^ (((x >> 7) & 3) << 4); }

// Stage a 128-row x 64-byte (8KB) tile into `region` (linear LDS dest,
// pre-swizzled per-lane global source so that reads with swz() see logical).
__device__ __forceinline__ void stage_tile(const char* gbase, size_t row_stride,
                                           char* region, int t) {
  const int lane = t & 63, w = t >> 6;
#pragma unroll
  for (int pass = 0; pass < 2; ++pass) {
    int d = pass * 4096 + w * 1024 + lane * 16;
    int l = swz(d);
    gl_lds16(gbase + (size_t)(l >> 6) * row_stride + (l & 63),
             region + pass * 4096 + w * 1024);
  }
}

// Load one 16x32 fp16 MFMA fragment: lane holds row (lane&15)+rowbase,
// 8 contiguous k at chunk (lane>>4).
__device__ __forceinline__ half8 frag_ld(const char* region, int rowbase, int lane) {
  int lb = (rowbase + (lane & 15)) * 64 + (lane >> 4) * 16;
  return *(const half8*)(region + swz(lb));
}

// ---------------------------------------------------------------------------
// Kernel 1: KNN (unchanged — verified in round 1).
// ---------------------------------------------------------------------------
__global__ __launch_bounds__(256) void knn_kernel(
    const float* __restrict__ pcd, const float* __restrict__ pcd_fb,
    int* __restrict__ knn) {
  __shared__ float sx[SS], sy[SS], sz[SS], ss[SS];
  const int t = threadIdx.x;
  const int b = blockIdx.x >> 8;
  const int nbase = (blockIdx.x & 255) * 4;
  for (int s = t; s < SS; s += 256) {
    float x, y, z;
    if (s < NN) {
      x = pcd[(b * 3 + 0) * NN + s];
      y = pcd[(b * 3 + 1) * NN + s];
      z = pcd[(b * 3 + 2) * NN + s];
    } else {
      int s2 = s - NN;
      x = pcd_fb[(b * 3 + 0) * MM + s2];
      y = pcd_fb[(b * 3 + 1) * MM + s2];
      z = pcd_fb[(b * 3 + 2) * MM + s2];
    }
    sx[s] = x; sy[s] = y; sz[s] = z;
    ss[s] = x * x + y * y + z * z;
  }
  __syncthreads();
  const int wv = t >> 6, lane = t & 63;
  const int n = nbase + wv;
  const float qx = sx[n], qy = sy[n], qz = sz[n];
  const float qq = qx * qx + qy * qy + qz * qz;
  float d[32];
#pragma unroll
  for (int i = 0; i < 32; ++i) {
    int s = i * 64 + lane;
    d[i] = qq - 2.0f * (qx * sx[s] + qy * sy[s] + qz * sz[s]) + ss[s];
  }
  unsigned mask = 0;
  int win = -1;
#pragma unroll
  for (int r = 0; r < 16; ++r) {
    float best = 3.4e38f;
    int bi = 0x7fffffff;
#pragma unroll
    for (int i = 0; i < 32; ++i) {
      if (!((mask >> i) & 1) && d[i] < best) { best = d[i]; bi = i * 64 + lane; }
    }
#pragma unroll
    for (int off = 32; off >= 1; off >>= 1) {
      float ov = __shfl_xor(best, off);
      int oi = __shfl_xor(bi, off);
      if (ov < best || (ov == best && oi < bi)) { best = ov; bi = oi; }
    }
    if ((bi & 63) == lane) mask |= 1u << (bi >> 6);
    if (lane == r) win = bi;
  }
  if (lane < 16) knn[((size_t)b * NN + n) * KK + lane] = win;
}

// ---------------------------------------------------------------------------
// Kernel 2: repack attn weights to fp16 (k-contiguous rows) + fold BN1.
// ---------------------------------------------------------------------------
__global__ __launch_bounds__(256) void repack(
    const float* __restrict__ w1, const float* __restrict__ w2,
    const float* __restrict__ g, const float* __restrict__ beta,
    const float* __restrict__ m, const float* __restrict__ v,
    const float* __restrict__ b1,
    _Float16* __restrict__ w1h, _Float16* __restrict__ w2h,
    float* __restrict__ s1, float* __restrict__ t1) {
  int i = blockIdx.x * 256 + threadIdx.x;
  for (int e = i; e < AH * CC; e += gridDim.x * 256) w1h[e] = (_Float16)w1[e];
  for (int e = i; e < CC * AH; e += gridDim.x * 256) w2h[e] = (_Float16)w2[e];
  if (i < AH) {
    float sc = g[i] * rsqrtf(v[i] + EPSV);
    s1[i] = sc;
    t1[i] = (b1[i] - m[i]) * sc + beta[i];
  }
}

// ---------------------------------------------------------------------------
// Kernel 3: gather + pos MLP; writes X=[col][k] fp16 and V=[c][col] f32.
// One block per query. h1r stored [k][h] so per-thread reads are contiguous.
// ---------------------------------------------------------------------------
__global__ __launch_bounds__(256) void build_xv(
    int b,
    const float* __restrict__ pcd, const float* __restrict__ feat,
    const float* __restrict__ pcd_fb, const float* __restrict__ feat_fb,
    const float* __restrict__ pw1, const float* __restrict__ pb1,
    const float* __restrict__ pg, const float* __restrict__ pbeta,
    const float* __restrict__ pm, const float* __restrict__ pv,
    const float* __restrict__ pw2, const float* __restrict__ pb2,
    const int* __restrict__ knn, _Float16* __restrict__ Xp,
    float* __restrict__ Vp) {
  __shared__ int idx_sh[KK];
  __shared__ float prel[3][KK];
  __shared__ float h1r[KK][PH + 4];
  const int t = threadIdx.x;
  const int n = blockIdx.x;
  if (t < KK) idx_sh[t] = knn[((size_t)b * NN + n) * KK + t];
  __syncthreads();
  if (t < 3 * KK) {
    int dd = t >> 4, k = t & 15;
    int s = idx_sh[k];
    float gp = (s < NN) ? pcd[(b * 3 + dd) * NN + s]
                        : pcd_fb[(b * 3 + dd) * MM + (s - NN)];
    prel[dd][k] = pcd[(b * 3 + dd) * NN + n] - gp;
  }
  __syncthreads();
  for (int e = t; e < PH * KK; e += 256) {
    int h = e >> 4, k = e & 15;
    float val = pb1[h] + pw1[h * 3 + 0] * prel[0][k] + pw1[h * 3 + 1] * prel[1][k]
              + pw1[h * 3 + 2] * prel[2][k];
    float sc = pg[h] * rsqrtf(pv[h] + EPSV);
    val = (val - pm[h]) * sc + pbeta[h];
    h1r[k][h] = fmaxf(val, 0.0f);
  }
  __syncthreads();
  const int k = t & 15, cg = t >> 4;  // this thread: neighbor k, c in [cg*32, cg*32+32)
  const int s = idx_sh[k];
  f32x4 hv[16];
#pragma unroll
  for (int q = 0; q < 16; ++q) hv[q] = *(const f32x4*)&h1r[k][q * 4];
  const float* featb = feat + (size_t)b * CC * NN;
  const float* gfb = (s < NN) ? feat + (size_t)b * CC * NN + s
                              : feat_fb + (size_t)b * CC * MM + (s - NN);
  _Float16* xdst = Xp + ((size_t)n * KK + k) * CC + cg * 32;
#pragma unroll
  for (int qq = 0; qq < 4; ++qq) {
    half8 xv;
#pragma unroll
    for (int j = 0; j < 8; ++j) {
      int c = cg * 32 + qq * 8 + j;
      float fq = featb[(size_t)c * NN + n];
      float gf = gfb[(size_t)c * NN];  // NN == MM so stride is valid for both
      float pe = pb2[c];
      const f32x4* w2r = (const f32x4*)(pw2 + (size_t)c * PH);
#pragma unroll
      for (int q = 0; q < 16; ++q) {
        f32x4 w4 = w2r[q];
        pe += w4.x * hv[q].x + w4.y * hv[q].y + w4.z * hv[q].z + w4.w * hv[q].w;
      }
      xv[j] = (_Float16)(fq - gf + pe);
      Vp[(size_t)c * COLS + n * KK + k] = gf + pe;
    }
    *((half8*)xdst + qq) = xv;
  }
}

// ---------------------------------------------------------------------------
// Kernel 4: gemm1 = relu(bn(W1 @ X)) via f16 MFMA, 128x128 tile, BK=32.
// Epilogue transposes the tile through LDS -> A1R in [col][h] fp16 layout.
// ---------------------------------------------------------------------------
__global__ __launch_bounds__(256) void gemm1_f16(
    const _Float16* __restrict__ Wh, const float* __restrict__ s1,
    const float* __restrict__ t1, const _Float16* __restrict__ Xp,
    _Float16* __restrict__ A1Rp) {
  __shared__ char lds[34816];  // 16KB staging, reused as 4x8704B transpose buf
  char* As = lds;
  char* Bs = lds + 8192;
  const int t = threadIdx.x, lane = t & 63, w = t >> 6;
  const int wr = w >> 1, wc = w & 1;
  const int h0 = blockIdx.y * 128;
  const int col0 = blockIdx.x * 128;
  f32x4 acc[4][4];
  f32x4 zz = {0.f, 0.f, 0.f, 0.f};
#pragma unroll
  for (int m = 0; m < 4; ++m)
#pragma unroll
    for (int n = 0; n < 4; ++n) acc[m][n] = zz;
  for (int s = 0; s < CC / 32; ++s) {
    const int k0 = s * 32;
    stage_tile((const char*)(Wh + (size_t)h0 * CC + k0), CC * 2, As, t);
    stage_tile((const char*)(Xp + (size_t)col0 * CC + k0), CC * 2, Bs, t);
    __syncthreads();
    half8 a[4], bf[4];
#pragma unroll
    for (int m = 0; m < 4; ++m) a[m] = frag_ld(As, wr * 64 + m * 16, lane);
#pragma unroll
    for (int n = 0; n < 4; ++n) bf[n] = frag_ld(Bs, wc * 64 + n * 16, lane);
#pragma unroll
    for (int m = 0; m < 4; ++m)
#pragma unroll
      for (int n = 0; n < 4; ++n)
        acc[m][n] = __builtin_amdgcn_mfma_f32_16x16x32_f16(a[m], bf[n], acc[m][n], 0, 0, 0);
    __syncthreads();
  }
  // Epilogue: BN+ReLU, fp16, per-wave LDS transpose ([64 col][68 h] fp16).
  char* tb = lds + w * 8704;
#pragma unroll
  for (int m = 0; m < 4; ++m) {
    float sc[4], sh[4];
#pragma unroll
    for (int r = 0; r < 4; ++r) {
      int h = h0 + wr * 64 + m * 16 + (lane >> 4) * 4 + r;
      sc[r] = s1[h];
      sh[r] = t1[h];
    }
#pragma unroll
    for (int n = 0; n < 4; ++n) {
      half4 p;
#pragma unroll
      for (int r = 0; r < 4; ++r)
        p[r] = (_Float16)fmaxf(acc[m][n][r] * sc[r] + sh[r], 0.0f);
      int col_l = n * 16 + (lane & 15);
      *(half4*)(tb + col_l * 136 + (m * 16 + (lane >> 4) * 4) * 2) = p;
    }
  }
  __syncthreads();
  char* dstbase = (char*)A1Rp + (size_t)(h0 + wr * 64) * 2;
#pragma unroll
  for (int pass = 0; pass < 8; ++pass) {
    int col_l = (lane >> 3) + pass * 8;
    int chunk = lane & 7;
    *(half8*)(dstbase + (size_t)(col0 + wc * 64 + col_l) * (AH * 2) + chunk * 16) =
        *(const half8*)(tb + col_l * 136 + chunk * 16);
  }
}

// ---------------------------------------------------------------------------
// Kernel 5: gemm2 = W2 @ A1R via f16 MFMA; fused softmax(K=16) + V-weighted
// sum epilogue (shuffle reductions over the 16 neighbor lanes). b2 cancels
// in softmax and is omitted. No max-subtraction: |logit| small by norms.
// ---------------------------------------------------------------------------
__global__ __launch_bounds__(256) void gemm2_f16(
    int b, const _Float16* __restrict__ Wh, const _Float16* __restrict__ A1Rp,
    const float* __restrict__ Vp, float* __restrict__ out) {
  __shared__ char lds[16384];
  char* As = lds;
  char* Bs = lds + 8192;
  const int t = threadIdx.x, lane = t & 63, w = t >> 6;
  const int wr = w >> 1, wc = w & 1;
  const int c0 = blockIdx.y * 128;
  const int col0 = blockIdx.x * 128;
  f32x4 acc[4][4];
  f32x4 zz = {0.f, 0.f, 0.f, 0.f};
#pragma unroll
  for (int m = 0; m < 4; ++m)
#pragma unroll
    for (int n = 0; n < 4; ++n) acc[m][n] = zz;
  for (int s = 0; s < AH / 32; ++s) {
    const int k0 = s * 32;
    stage_tile((const char*)(Wh + (size_t)c0 * AH + k0), AH * 2, As, t);
    stage_tile((const char*)(A1Rp + (size_t)col0 * AH + k0), AH * 2, Bs, t);
    __syncthreads();
    half8 a[4], bf[4];
#pragma unroll
    for (int m = 0; m < 4; ++m) a[m] = frag_ld(As, wr * 64 + m * 16, lane);
#pragma unroll
    for (int n = 0; n < 4; ++n) bf[n] = frag_ld(Bs, wc * 64 + n * 16, lane);
#pragma unroll
    for (int m = 0; m < 4; ++m)
#pragma unroll
      for (int n = 0; n < 4; ++n)
        acc[m][n] = __builtin_amdgcn_mfma_f32_16x16x32_f16(a[m], bf[n], acc[m][n], 0, 0, 0);
    __syncthreads();
  }
  // Fused softmax + weighted-V epilogue. Lanes sharing (lane>>4) hold the 16
  // neighbors (lane&15 = k) of one (c, query) pair.
#pragma unroll
  for (int m = 0; m < 4; ++m)
#pragma unroll
    for (int n = 0; n < 4; ++n) {
      int cg2 = col0 + wc * 64 + n * 16 + (lane & 15);
      int nq = cg2 >> 4;
#pragma unroll
      for (int r = 0; r < 4; ++r) {
        int c = c0 + wr * 64 + m * 16 + (lane >> 4) * 4 + r;
        float e = __expf(acc[m][n][r]);
        float se = e;
#pragma unroll
        for (int o = 8; o >= 1; o >>= 1) se += __shfl_xor(se, o);
        float vv = Vp[(size_t)c * COLS + cg2];
        float te = e * vv;
#pragma unroll
        for (int o = 8; o >= 1; o >>= 1) te += __shfl_xor(te, o);
        if ((lane & 15) == 0) out[((size_t)b * CC + c) * NN + nq] = __fdividef(te, se);
      }
    }
}

// ---------------------------------------------------------------------------
extern "C" void kernel_launch(void* const* d_in, const int* in_sizes, int n_in,
                              void* d_out, int out_size, void* d_ws, size_t ws_size,
                              hipStream_t stream) {
  const float* pcd     = (const float*)d_in[0];
  const float* feat    = (const float*)d_in[1];
  const float* pcd_fb  = (const float*)d_in[2];
  const float* feat_fb = (const float*)d_in[3];
  const float* pw1     = (const float*)d_in[4];
  const float* pb1     = (const float*)d_in[5];
  const float* pg      = (const float*)d_in[6];
  const float* pbeta   = (const float*)d_in[7];
  const float* pm      = (const float*)d_in[8];
  const float* pv      = (const float*)d_in[9];
  const float* pw2     = (const float*)d_in[10];
  const float* pb2     = (const float*)d_in[11];
  const float* aw1     = (const float*)d_in[12];
  const float* ab1     = (const float*)d_in[13];
  const float* ag      = (const float*)d_in[14];
  const float* abeta   = (const float*)d_in[15];
  const float* am      = (const float*)d_in[16];
  const float* av      = (const float*)d_in[17];
  const float* aw2     = (const float*)d_in[18];
  const float* ab2     = (const float*)d_in[19];
  (void)ab2;  // cancels in softmax
  float* out = (float*)d_out;

  char* ws = (char*)d_ws;
  size_t off = 0;
  int* idx_ws = (int*)(ws + off);      off += (size_t)BB * NN * KK * sizeof(int);
  _Float16* W1h = (_Float16*)(ws + off); off += (size_t)AH * CC * 2;
  _Float16* W2h = (_Float16*)(ws + off); off += (size_t)CC * AH * 2;
  float* s1 = (float*)(ws + off);      off += AH * sizeof(float);
  float* t1 = (float*)(ws + off);      off += AH * sizeof(float);
  off = (off + 255) & ~(size_t)255;
  _Float16* Xp = (_Float16*)(ws + off);   off += (size_t)COLS * CC * 2;   // 16.8 MB
  _Float16* A1Rp = (_Float16*)(ws + off); off += (size_t)COLS * AH * 2;   // 33.6 MB
  float* Vp = (float*)(ws + off);         off += (size_t)CC * COLS * 4;   // 33.6 MB

  knn_kernel<<<dim3(BB * NN / 4), 256, 0, stream>>>(pcd, pcd_fb, idx_ws);
  repack<<<dim3(512), 256, 0, stream>>>(aw1, aw2, ag, abeta, am, av, ab1,
                                        W1h, W2h, s1, t1);
  for (int b = 0; b < BB; ++b) {
    build_xv<<<dim3(NN), 256, 0, stream>>>(
        b, pcd, feat, pcd_fb, feat_fb,
        pw1, pb1, pg, pbeta, pm, pv, pw2, pb2, idx_ws, Xp, Vp);
    gemm1_f16<<<dim3(COLS / 128, AH / 128), 256, 0, stream>>>(W1h, s1, t1, Xp, A1Rp);
    gemm2_f16<<<dim3(COLS / 128, CC / 128), 256, 0, stream>>>(b, W2h, A1Rp, Vp, out);
  }
}